// Round 8
// baseline (108.092 us; speedup 1.0000x reference)
//
#include <hip/hip_runtime.h>

// QLinear: y[n,o] = round((sum_k (x[n,k]-xz)*(w[o,k]-wz) + bias[o]) * M + yz)
// N=65536, K=512, OUT=512.
// Exact i8 path: (x-128),(w-128) in [-128,127]; |dot+bias| < 2^24; f32 epilogue exact.
// R8: two-pass. xprep streams x f32 -> i8 once (pure stream, no sync structure).
//     qgemm: 64x64 full-K tiles, ALL fragments staged in one global_load_lds burst
//     (8 wave-instrs/wave, deep MLP), ONE barrier, pure LDS+MFMA, store burst.
//     2 blocks/CU co-resident overlap load/compute/store phases.

#define K_DIM 512
#define OUTF  512

typedef __attribute__((ext_vector_type(4))) int   i32x4;
typedef __attribute__((ext_vector_type(4))) float f32x4;
typedef __attribute__((ext_vector_type(4))) unsigned int u32x4;

__device__ __forceinline__ void gload16(const void* g, void* l) {
    __builtin_amdgcn_global_load_lds(
        (const __attribute__((address_space(1))) void*)g,
        (__attribute__((address_space(3))) void*)l, 16, 0, 0);
}

// ---------- prepass: weight int32 -> i8 (w - wz), row-major [o][k] ----------
__global__ void wprep(const int* __restrict__ W, unsigned int* __restrict__ Wb,
                      const float* __restrict__ wzp) {
    const int wz = __float2int_rn(wzp[0]);
    int idx = (blockIdx.x * blockDim.x + threadIdx.x) * 4;
    i32x4 w = *reinterpret_cast<const i32x4*>(W + idx);
    unsigned int p = ((unsigned int)(w[0] - wz) & 0xffu)
                   | (((unsigned int)(w[1] - wz) & 0xffu) << 8)
                   | (((unsigned int)(w[2] - wz) & 0xffu) << 16)
                   | (((unsigned int)(w[3] - wz) & 0xffu) << 24);
    Wb[idx >> 2] = p;
}

// ---------- prepass: x f32 -> i8 (x - xz), pure stream ----------
__global__ __launch_bounds__(256)
void xprep(const float* __restrict__ X, u32x4* __restrict__ Xb,
           const float* __restrict__ xzp) {
    const float xzf = xzp[0];
    size_t i = (size_t)blockIdx.x * blockDim.x + threadIdx.x;   // 16 floats each
    const f32x4* xp = reinterpret_cast<const f32x4*>(X) + i * 4;
    u32x4 o;
    #pragma unroll
    for (int q = 0; q < 4; ++q) {
        f32x4 v = xp[q];
        unsigned int b0 = (unsigned int)((int)(v[0] - xzf)) & 0xffu;
        unsigned int b1 = (unsigned int)((int)(v[1] - xzf)) & 0xffu;
        unsigned int b2 = (unsigned int)((int)(v[2] - xzf)) & 0xffu;
        unsigned int b3 = (unsigned int)((int)(v[3] - xzf)) & 0xffu;
        o[q] = b0 | (b1 << 8) | (b2 << 16) | (b3 << 24);
    }
    Xb[i] = o;
}

// ---------- main GEMM: 64x64 tile, full-K single-shot staging ----------
// 8192 blocks x 512 thr (8 waves). Waves 0-3 stage A-frags (rowgroup w, ks 0..7),
// waves 4-7 stage B-frags (colfrag w-4, ks 0..7). One fragment = one gload_lds
// (64 lanes x 16 B, lane-linear dest == MFMA fragment order; validated R3/R6/R7).
__global__ __launch_bounds__(512, 4)
void qgemm(const unsigned char* __restrict__ Xb,
           const unsigned char* __restrict__ Wb,
           const int* __restrict__ bias,
           const float* __restrict__ Mp,
           const float* __restrict__ yzp,
           float* __restrict__ Y) {
    __shared__ unsigned char lds[65536];   // A: 32 frags @ [0,32K), B: 32 @ [32K,64K)

    const int tid  = threadIdx.x;
    const int lane = tid & 63;
    const int wid  = tid >> 6;              // 0..7
    const int fr   = lane & 15;
    const int fq   = lane >> 4;

    // XCD swizzle: 8192 = 8 XCDs x 1024; within XCD, the 8 col-tiles of a
    // row-panel are consecutive -> x_i8 panel is read once from LLC, then L2-hit.
    const int b   = blockIdx.x;
    const int q   = b >> 3;                 // [0,1024)
    const int rp  = (b & 7) * 128 + (q >> 3);   // row-panel [0,1024)
    const int row0 = rp * 64;
    const int c0t  = (q & 7) * 64;          // col-tile base

    // ---- staging burst: 8 gload_lds per wave, all K in flight ----
    if (wid < 4) {
        const unsigned char* g = Xb + (size_t)(row0 + wid * 16 + fr) * K_DIM + fq * 16;
        #pragma unroll
        for (int ks = 0; ks < 8; ++ks)
            gload16(g + ks * 64, &lds[(wid * 8 + ks) * 1024]);
    } else {
        const int n = wid - 4;
        const unsigned char* g = Wb + (size_t)(c0t + n * 16 + fr) * K_DIM + fq * 16;
        #pragma unroll
        for (int ks = 0; ks < 8; ++ks)
            gload16(g + ks * 64, &lds[32768 + (n * 8 + ks) * 1024]);
    }

    // compute roles: wave = 16 rows x 32 cols
    const int wrow = wid >> 1;              // A rowgroup 0..3
    const int wcn  = (wid & 1) * 2;         // B frags wcn, wcn+1
    const int col0 = c0t + wcn * 16 + fr;
    const int bv0 = bias[col0];
    const int bv1 = bias[col0 + 16];
    i32x4 acc0 = {bv0, bv0, bv0, bv0};
    i32x4 acc1 = {bv1, bv1, bv1, bv1};

    __syncthreads();                        // single drain per block

    #pragma unroll
    for (int ks = 0; ks < 8; ++ks) {
        i32x4 af = *reinterpret_cast<const i32x4*>(&lds[(wrow * 8 + ks) * 1024 + lane * 16]);
        i32x4 b0 = *reinterpret_cast<const i32x4*>(&lds[32768 + (wcn * 8 + ks) * 1024 + lane * 16]);
        i32x4 b1 = *reinterpret_cast<const i32x4*>(&lds[32768 + ((wcn + 1) * 8 + ks) * 1024 + lane * 16]);
        acc0 = __builtin_amdgcn_mfma_i32_16x16x64_i8(af, b0, acc0, 0, 0, 0);
        acc1 = __builtin_amdgcn_mfma_i32_16x16x64_i8(af, b1, acc1, 0, 0, 0);
    }

    // epilogue: y = rintf(acc * M + yz)  (bias pre-folded)
    const float Mv = Mp[0], yz = yzp[0];
    const int row = row0 + wrow * 16 + fq * 4;
    float* yp = Y + (size_t)row * OUTF + col0;
    #pragma unroll
    for (int j = 0; j < 4; ++j) {
        yp[(size_t)j * OUTF]      = rintf((float)acc0[j] * Mv + yz);
        yp[(size_t)j * OUTF + 16] = rintf((float)acc1[j] * Mv + yz);
    }
}

// ---------- fallback (ws too small): R5 kernel minus nontemporal stores ----------
#define NT    8
#define LDAB  80
#define TILE_B (128 * LDAB)
#define BUF_B  (2 * TILE_B)

__global__ __launch_bounds__(512, 4)
void qgemm_fb(const float* __restrict__ X,
              const unsigned char* __restrict__ Wb,
              const int* __restrict__ bias,
              const float* __restrict__ Mp,
              const float* __restrict__ xzp,
              const float* __restrict__ yzp,
              float* __restrict__ Y) {
    __shared__ unsigned char lds[2 * BUF_B];

    const int tid  = threadIdx.x;
    const int lane = tid & 63;
    const int wid  = tid >> 6;
    const int wr   = wid >> 2;
    const int wc   = wid & 3;
    const int fr   = lane & 15;
    const int fq   = lane >> 4;

    const int b = blockIdx.x;
    const int lid = (b & 7) * 256 + (b >> 3);
    const int row0 = (lid >> 2) * 128;
    const int n0   = (lid & 3) * 128;

    const float xzf = xzp[0];

    const int srow = tid >> 2;
    const int scol = (tid & 3) * 16;
    const float* xbase = X + (size_t)(row0 + srow) * K_DIM + scol;
    const unsigned char* wbase = Wb + (size_t)(n0 + srow) * K_DIM + scol;
    const int aoff = srow * LDAB + scol;
    const int boff = TILE_B + srow * LDAB + scol;

    f32x4 ra[2][4];
    i32x4 rb[2];

    auto stage = [&](int t) {
        const int s = t & 1;
        const float* xp = xbase + t * 64;
        #pragma unroll
        for (int qq = 0; qq < 4; ++qq)
            ra[s][qq] = *reinterpret_cast<const f32x4*>(xp + qq * 4);
        rb[s] = *reinterpret_cast<const i32x4*>(wbase + t * 64);
    };
    auto convwrite = [&](int t, int buf) {
        const int s = t & 1;
        const int ab = buf * BUF_B;
        i32x4 pa;
        #pragma unroll
        for (int qq = 0; qq < 4; ++qq) {
            unsigned int u0 = (unsigned int)((int)(ra[s][qq][0] - xzf)) & 0xffu;
            unsigned int u1 = (unsigned int)((int)(ra[s][qq][1] - xzf)) & 0xffu;
            unsigned int u2 = (unsigned int)((int)(ra[s][qq][2] - xzf)) & 0xffu;
            unsigned int u3 = (unsigned int)((int)(ra[s][qq][3] - xzf)) & 0xffu;
            pa[qq] = (int)(u0 | (u1 << 8) | (u2 << 16) | (u3 << 24));
        }
        *reinterpret_cast<i32x4*>(&lds[ab + aoff]) = pa;
        *reinterpret_cast<i32x4*>(&lds[ab + boff]) = rb[s];
    };

    const int c0 = n0 + wc * 32;
    const int bv0 = bias[c0 + fr];
    const int bv1 = bias[c0 + 16 + fr];
    i32x4 acc[4][2];
    #pragma unroll
    for (int m = 0; m < 4; ++m) {
        acc[m][0] = i32x4{bv0, bv0, bv0, bv0};
        acc[m][1] = i32x4{bv1, bv1, bv1, bv1};
    }

    const int aro = (wr * 64 + fr) * LDAB + fq * 16;
    const int bro = TILE_B + (wc * 32 + fr) * LDAB + fq * 16;

    auto compute = [&](int buf) {
        const int ab = buf * BUF_B;
        i32x4 af[4], bf[2];
        #pragma unroll
        for (int m = 0; m < 4; ++m)
            af[m] = *reinterpret_cast<const i32x4*>(&lds[ab + aro + m * 16 * LDAB]);
        #pragma unroll
        for (int n = 0; n < 2; ++n)
            bf[n] = *reinterpret_cast<const i32x4*>(&lds[ab + bro + n * 16 * LDAB]);
        #pragma unroll
        for (int m = 0; m < 4; ++m)
            #pragma unroll
            for (int n = 0; n < 2; ++n)
                acc[m][n] = __builtin_amdgcn_mfma_i32_16x16x64_i8(
                    af[m], bf[n], acc[m][n], 0, 0, 0);
    };

    stage(0);
    stage(1);
    convwrite(0, 0);
    __syncthreads();

    #pragma unroll
    for (int t = 0; t < NT; ++t) {
        if (t + 2 < NT) stage(t + 2);
        compute(t & 1);
        if (t + 1 < NT) convwrite(t + 1, (t + 1) & 1);
        __syncthreads();
    }

    const float Mv = Mp[0], yz = yzp[0];
    #pragma unroll
    for (int n = 0; n < 2; ++n) {
        const int col = c0 + n * 16 + fr;
        #pragma unroll
        for (int m = 0; m < 4; ++m) {
            const int row = row0 + wr * 64 + m * 16 + fq * 4;
            float* yp = Y + (size_t)row * OUTF + col;
            #pragma unroll
            for (int j = 0; j < 4; ++j)
                yp[(size_t)j * OUTF] = rintf((float)acc[m][n][j] * Mv + yz);
        }
    }
}

extern "C" void kernel_launch(void* const* d_in, const int* in_sizes, int n_in,
                              void* d_out, int out_size, void* d_ws, size_t ws_size,
                              hipStream_t stream) {
    const float* x    = (const float*)d_in[0];
    const int*   w    = (const int*)d_in[1];
    const int*   bias = (const int*)d_in[2];
    const float* M    = (const float*)d_in[3];
    const float* xz   = (const float*)d_in[4];
    const float* wz   = (const float*)d_in[5];
    const float* yz   = (const float*)d_in[6];
    float* y = (float*)d_out;

    unsigned char* Wb  = (unsigned char*)d_ws;          // 256 KB
    unsigned char* Xbp = Wb + 256 * 1024;               // 32 MB
    const size_t need = 256 * 1024 + (size_t)65536 * 512;

    wprep<<<256, 256, 0, stream>>>(w, (unsigned int*)Wb, wz);

    if (ws_size >= need) {
        xprep<<<8192, 256, 0, stream>>>(x, (u32x4*)Xbp, xz);
        qgemm<<<8192, 512, 0, stream>>>(Xbp, Wb, bias, M, yz, y);
    } else {
        qgemm_fb<<<2048, 512, 0, stream>>>(x, Wb, bias, M, xz, yz, y);
    }
}

// Round 9
// 67.978 us; speedup vs baseline: 1.5901x; 1.5901x over previous
//
#include <hip/hip_runtime.h>

// QLinear: y[n,o] = round((sum_k (x[n,k]-xz)*(w[o,k]-wz) + bias[o]) * M + yz)
// N=65536, K=512, OUT=512.
// Exact i8 path: (x-128),(w-128) in [-128,127]; |dot+bias| < 2^24; f32 epilogue exact.
// R9: R5 skeleton (reg-staged dist-2 A, plain __syncthreads) with 128x256 tile:
//     halves the dominant f32 A-traffic (537->268 MB through LLC). B staged via
//     global_load_lds into fragment-major LDS (i8 passthrough, 0 regs, 0 conflicts).

#define K_DIM 512
#define OUTF  512
#define NT    8            // K_DIM / 64
#define LDAB  80           // A LDS row stride (bytes)
#define A_BYTES (128 * LDAB)          // 10240
#define B_OFF   A_BYTES               // B region: 16 frags x 1024 B
#define BUF_B   (A_BYTES + 16 * 1024) // 26624 per buffer

typedef __attribute__((ext_vector_type(4))) int   i32x4;
typedef __attribute__((ext_vector_type(4))) float f32x4;

__device__ __forceinline__ void gload16(const void* g, void* l) {
    __builtin_amdgcn_global_load_lds(
        (const __attribute__((address_space(1))) void*)g,
        (__attribute__((address_space(3))) void*)l, 16, 0, 0);
}

// ---------- prepass: weight int32 -> i8 (w - wz), row-major [o][k] ----------
__global__ void wprep(const int* __restrict__ W, unsigned int* __restrict__ Wb,
                      const float* __restrict__ wzp) {
    const int wz = __float2int_rn(wzp[0]);
    int idx = (blockIdx.x * blockDim.x + threadIdx.x) * 4;
    i32x4 w = *reinterpret_cast<const i32x4*>(W + idx);
    unsigned int p = ((unsigned int)(w[0] - wz) & 0xffu)
                   | (((unsigned int)(w[1] - wz) & 0xffu) << 8)
                   | (((unsigned int)(w[2] - wz) & 0xffu) << 16)
                   | (((unsigned int)(w[3] - wz) & 0xffu) << 24);
    Wb[idx >> 2] = p;
}

__global__ __launch_bounds__(512, 4)
void qgemm(const float* __restrict__ X,
           const unsigned char* __restrict__ Wb,
           const int* __restrict__ bias,
           const float* __restrict__ Mp,
           const float* __restrict__ xzp,
           const float* __restrict__ yzp,
           float* __restrict__ Y) {
    __shared__ unsigned char lds[2][BUF_B];   // 53248 B total

    const int tid  = threadIdx.x;
    const int lane = tid & 63;
    const int wid  = tid >> 6;                 // 0..7
    const int wr   = wid >> 2;                 // row 64-strip (0..1)
    const int wc   = wid & 3;                  // col 64-strip (0..3)
    const int fr   = lane & 15;
    const int fq   = lane >> 4;

    // XCD-contiguous bijective swizzle (1024 = 8 * 128); col-tile fastest so the
    // 2 col-blocks sharing an x row-panel co-reside on one XCD's L2.
    const int b = blockIdx.x;
    const int lid = (b & 7) * 128 + (b >> 3);
    const int row0 = (lid >> 1) * 128;
    const int n0   = (lid & 1) * 256;

    const float xzf = xzp[0];

    // A staging map (R5-proven): thread -> row tid>>2 (0..127), 16 f32 at col (tid&3)*16
    const int srow = tid >> 2;
    const float* xbase = X + (size_t)(row0 + srow) * K_DIM + (tid & 3) * 16;
    const int aoff = srow * LDAB + (tid & 3) * 16;

    // B staging: wave wid stages frags 2*wid, 2*wid+1 via global_load_lds.
    // Frag f = cols n0+f*16..+16, lane l -> col (l&15), k-bytes (l>>4)*16.
    // Dest lane-linear (gload constraint) == MFMA B fragment order (validated R3/R8).
    const unsigned char* wbase = Wb + (size_t)(n0 + wid * 32 + fr) * K_DIM + fq * 16;
    const int ldsB = B_OFF + wid * 2048;

    f32x4 ra[2][4];                           // dist-2 staging sets for A

    auto stageA = [&](int t) {
        const int s = t & 1;
        const float* xp = xbase + t * 64;
        #pragma unroll
        for (int q = 0; q < 4; ++q)
            ra[s][q] = *reinterpret_cast<const f32x4*>(xp + q * 4);
    };
    auto gloadB = [&](int t, int buf) {
        const unsigned char* g = wbase + t * 64;
        gload16(g,               &lds[buf][ldsB]);
        gload16(g + 16 * K_DIM,  &lds[buf][ldsB + 1024]);
    };
    auto convwriteA = [&](int t) {
        const int s = t & 1;
        i32x4 pa;
        #pragma unroll
        for (int q = 0; q < 4; ++q) {
            unsigned int u0 = (unsigned int)((int)(ra[s][q][0] - xzf)) & 0xffu;
            unsigned int u1 = (unsigned int)((int)(ra[s][q][1] - xzf)) & 0xffu;
            unsigned int u2 = (unsigned int)((int)(ra[s][q][2] - xzf)) & 0xffu;
            unsigned int u3 = (unsigned int)((int)(ra[s][q][3] - xzf)) & 0xffu;
            pa[q] = (int)(u0 | (u1 << 8) | (u2 << 16) | (u3 << 24));
        }
        *reinterpret_cast<i32x4*>(&lds[s][aoff]) = pa;
    };

    // bias folded into accumulator init; wave tile 64x64: acc[m][n]
    const int c0 = n0 + wc * 64;
    i32x4 acc[4][4];
    #pragma unroll
    for (int n = 0; n < 4; ++n) {
        const int bv = bias[c0 + n * 16 + fr];
        #pragma unroll
        for (int m = 0; m < 4; ++m)
            acc[m][n] = i32x4{bv, bv, bv, bv};
    }

    const int aro = (wr * 64 + fr) * LDAB + fq * 16;

    auto compute = [&](int t) {
        const int s = t & 1;
        i32x4 bf[4];
        #pragma unroll
        for (int n = 0; n < 4; ++n)
            bf[n] = *reinterpret_cast<const i32x4*>(&lds[s][B_OFF + (wc * 4 + n) * 1024 + lane * 16]);
        #pragma unroll
        for (int m = 0; m < 4; ++m) {
            i32x4 af = *reinterpret_cast<const i32x4*>(&lds[s][aro + m * 16 * LDAB]);
            #pragma unroll
            for (int n = 0; n < 4; ++n)
                acc[m][n] = __builtin_amdgcn_mfma_i32_16x16x64_i8(
                    af, bf[n], acc[m][n], 0, 0, 0);
        }
    };

    // prologue: A t=0,1 in flight; B t=0 in flight; write A t=0; drain all
    stageA(0);
    stageA(1);
    gloadB(0, 0);
    convwriteA(0);
    __syncthreads();

    #pragma unroll
    for (int t = 0; t < NT; ++t) {
        if (t + 2 < NT) stageA(t + 2);            // far-ahead A issue first
        if (t + 1 < NT) gloadB(t + 1, (t + 1) & 1);
        compute(t);
        if (t + 1 < NT) convwriteA(t + 1);        // consumes 1-iter-old A loads
        __syncthreads();
    }

    // epilogue: y = rintf(acc * M + yz)  (bias pre-folded)
    const float Mv = Mp[0], yz = yzp[0];
    #pragma unroll
    for (int n = 0; n < 4; ++n) {
        const int col = c0 + n * 16 + fr;
        #pragma unroll
        for (int m = 0; m < 4; ++m) {
            const int row = row0 + wr * 64 + m * 16 + fq * 4;
            float* yp = Y + (size_t)row * OUTF + col;
            #pragma unroll
            for (int j = 0; j < 4; ++j)
                yp[(size_t)j * OUTF] = rintf((float)acc[m][n][j] * Mv + yz);
        }
    }
}

extern "C" void kernel_launch(void* const* d_in, const int* in_sizes, int n_in,
                              void* d_out, int out_size, void* d_ws, size_t ws_size,
                              hipStream_t stream) {
    const float* x    = (const float*)d_in[0];
    const int*   w    = (const int*)d_in[1];
    const int*   bias = (const int*)d_in[2];
    const float* M    = (const float*)d_in[3];
    const float* xz   = (const float*)d_in[4];
    const float* wz   = (const float*)d_in[5];
    const float* yz   = (const float*)d_in[6];
    float* y = (float*)d_out;

    unsigned int* Wb = (unsigned int*)d_ws;     // 512*512 i8 = 256 KB

    wprep<<<256, 256, 0, stream>>>(w, Wb, wz);
    qgemm<<<1024, 512, 0, stream>>>(x, (const unsigned char*)Wb, bias, M, xz, yz, y);
}